// Round 11
// baseline (203.922 us; speedup 1.0000x reference)
//
#include <hip/hip_runtime.h>
#include <hip/hip_bf16.h>
#include <math.h>

#define NB 2
#define NN 512
#define CSD 384
#define CZD 128
#define NH 12
#define NC 16
#define NPQ 4
#define NPV 8
#define HC 192
#define QPDIM 144
#define FEATD 2112
#define WPT 0.13608276348795434f   // sqrt(1/(3*PQ*4.5))
#define RS3C 0.14433756729740643f  // sqrt(1/(3*C))
#define RS3 0.5773502691896258f    // sqrt(1/3)

typedef __attribute__((ext_vector_type(8))) short short8;
typedef __attribute__((ext_vector_type(4))) float f32x4;

static __device__ inline unsigned short f2bf(float x) {
    __hip_bfloat16 h = __float2bfloat16(x);
    return *reinterpret_cast<unsigned short*>(&h);
}
static __device__ inline unsigned short bflo(float x) {
    __hip_bfloat16 h = __float2bfloat16(x);
    return f2bf(x - __bfloat162float(h));
}

// ---------------- k_cvt ----------------
#define R_S0 393216
#define R_S1 (R_S0 + 73728)
#define R_S2 (R_S1 + 147456)
#define R_S3 (R_S2 + 55296)
#define R_S4 (R_S3 + 165888)
#define R_S5 (R_S4 + 811008)
#define R_S6 (R_S5 + 2048)
__global__ __launch_bounds__(256) void k_cvt(
    const float* __restrict__ single, const float* __restrict__ wq,
    const float* __restrict__ wkv, const float* __restrict__ wqp,
    const float* __restrict__ wkvp, const float* __restrict__ wo,
    const float* __restrict__ wb,
    unsigned short* __restrict__ singleb, unsigned short* __restrict__ wallb,
    unsigned short* __restrict__ wob, unsigned short* __restrict__ wbb)
{
    int gid = blockIdx.x * 256 + threadIdx.x;
    int e = gid * 4;
    if (e >= R_S6) return;
    if (e >= R_S5) {
        int c = e - R_S5;
        int hh = c >> 7;
        ushort4 o;
        if (hh < 12) {
            float4 v = *(const float4*)(wb + hh * 128 + (c & 127));
            o.x = f2bf(v.x); o.y = f2bf(v.y); o.z = f2bf(v.z); o.w = f2bf(v.w);
        } else { o.x = 0; o.y = 0; o.z = 0; o.w = 0; }
        *(ushort4*)(wbb + c) = o;
        return;
    }
    const float* src; unsigned short* dst;
    if (e < R_S0)      { src = single + e;          dst = singleb + e; }
    else if (e < R_S1) { src = wq + (e - R_S0);     dst = wallb + (e - R_S0); }
    else if (e < R_S2) { src = wkv + (e - R_S1);    dst = wallb + 73728 + (e - R_S1); }
    else if (e < R_S3) { src = wqp + (e - R_S2);    dst = wallb + 221184 + (e - R_S2); }
    else if (e < R_S4) { src = wkvp + (e - R_S3);   dst = wallb + 276480 + (e - R_S3); }
    else               { src = wo + (e - R_S4);     dst = wob + (e - R_S4); }
    float4 v = *(const float4*)src;
    ushort4 o;
    o.x = f2bf(v.x); o.y = f2bf(v.y); o.z = f2bf(v.z); o.w = f2bf(v.w);
    *(ushort4*)dst = o;
}

// ---------------- k_gemm1 ----------------
__global__ __launch_bounds__(256) void k_gemm1(
    const unsigned short* __restrict__ A, const unsigned short* __restrict__ Bm,
    float* __restrict__ Cr)
{
    int w = threadIdx.x >> 6, lane = threadIdx.x & 63;
    int rt = blockIdx.x;
    int ct = blockIdx.y * 4 + w;
    int r = lane & 15, kq = lane >> 4;
    const unsigned short* ap = A  + (size_t)(rt * 16 + r) * 384 + kq * 8;
    const unsigned short* bp = Bm + (size_t)(ct * 16 + r) * 384 + kq * 8;
    f32x4 acc = {0.f, 0.f, 0.f, 0.f};
    #pragma unroll 4
    for (int ks = 0; ks < 12; ++ks) {
        short8 av = *(const short8*)(ap + ks * 32);
        short8 bv = *(const short8*)(bp + ks * 32);
        acc = __builtin_amdgcn_mfma_f32_16x16x32_bf16(av, bv, acc, 0, 0, 0);
    }
    int crow = rt * 16 + kq * 4;
    int ccol = ct * 16 + r;
    #pragma unroll
    for (int i = 0; i < 4; ++i)
        Cr[(size_t)(crow + i) * 1152 + ccol] = acc[i];
}

// ---------------- k_post ----------------
__global__ __launch_bounds__(256) void k_post(
    const float* __restrict__ praw, const float* __restrict__ rot, const float* __restrict__ trans,
    const float* __restrict__ hw,
    const float* __restrict__ bq, const float* __restrict__ bkv,
    const float* __restrict__ bqp, const float* __restrict__ bkvp,
    unsigned short* __restrict__ vallT2,
    unsigned short* __restrict__ qhat, unsigned short* __restrict__ khat,
    float* __restrict__ qn2, float* __restrict__ kn2)
{
    __shared__ float s_q[192], s_k[192], s_v[192], s_qp[QPDIM], s_kvp[432];
    __shared__ float s_qg[144], s_kg[144], s_vg[288];
    __shared__ float s_sh[12];
    const int t = threadIdx.x;
    const int row = blockIdx.x;
    const int b = row >> 9;
    const int i = row & 511;

    if (t < 12) {
        float sp = log1pf(expf(hw[t]));
        s_sh[t] = RS3C / (WPT * sp);
    }
    const float* pr = praw + (size_t)row * 1152;
    for (int idx = t; idx < 1152; idx += 256) {
        float v = pr[idx];
        if (idx < 192) {
            s_q[idx] = v + bq[idx];
        } else if (idx < 576) {
            int f = idx - 192; float x = v + bkv[f];
            int h = f >> 5, cc = f & 31;
            if (cc < 16) s_k[h * 16 + cc] = x;
            else         s_v[h * 16 + cc - 16] = x;
        } else if (idx < 720) {
            int f = idx - 576; s_qp[f] = v + bqp[f];
        } else {
            int f = idx - 720; s_kvp[f] = v + bkvp[f];
        }
    }
    __syncthreads();

    if (t < 192) {
        const float* R = rot + (size_t)row * 9;
        const float* T = trans + (size_t)row * 3;
        float lx, ly, lz; float* dst;
        if (t < 48) {
            lx = s_qp[t]; ly = s_qp[48 + t]; lz = s_qp[96 + t];
            dst = s_qg + t * 3;
        } else if (t < 96) {
            int idx = t - 48; int fb = (idx >> 2) * 12 + (idx & 3);
            lx = s_kvp[fb]; ly = s_kvp[144 + fb]; lz = s_kvp[288 + fb];
            dst = s_kg + idx * 3;
        } else {
            int idx = t - 96; int fb = (idx >> 3) * 12 + 4 + (idx & 7);
            lx = s_kvp[fb]; ly = s_kvp[144 + fb]; lz = s_kvp[288 + fb];
            dst = s_vg + idx * 3;
        }
        dst[0] = R[0] * lx + R[1] * ly + R[2] * lz + T[0];
        dst[1] = R[3] * lx + R[4] * ly + R[5] * lz + T[1];
        dst[2] = R[6] * lx + R[7] * ly + R[8] * lz + T[2];
    }
    __syncthreads();

    if (t < 24) {
        int h = t % 12;
        const float* g = (t < 12) ? (s_qg + h * 12) : (s_kg + h * 12);
        float s = 0.f;
        #pragma unroll
        for (int e = 0; e < 12; ++e) s += g[e] * g[e];
        float* dst = (t < 12) ? qn2 : kn2;
        dst[((size_t)b * 12 + h) * 512 + i] = s;
    }

    for (int c = t; c < 768; c += 256) {
        int h = c >> 6, cp = c & 63;
        unsigned short v;
        if (cp < 16)      v = f2bf(s_v[h * 16 + cp]);
        else if (cp < 40) v = f2bf(s_vg[h * 24 + cp - 16]);
        else              v = bflo(s_vg[h * 24 + cp - 40]);
        vallT2[((size_t)(b * 12 + h) * 64 + cp) * 512 + i] = v;
    }

    for (int idx = t; idx < 768; idx += 256) {
        int side = idx >= 384;
        int li = side ? (idx - 384) : idx;
        int h = li >> 5, s2 = li & 31;
        unsigned short o[2];
        #pragma unroll
        for (int u = 0; u < 2; ++u) {
            int k = 2 * s2 + u;
            unsigned short val = 0;
            if (!side) {
                if (k < 16)      val = f2bf(s_sh[h] * s_q[h * 16 + k]);
                else if (k < 28) val = f2bf(s_qg[h * 12 + k - 16]);
                else if (k < 40) val = f2bf(s_qg[h * 12 + k - 28]);
                else if (k < 52) val = bflo(s_qg[h * 12 + k - 40]);
            } else {
                if (k < 16)      val = f2bf(s_k[h * 16 + k]);
                else if (k < 28) val = f2bf(s_kg[h * 12 + k - 16]);
                else if (k < 40) val = bflo(s_kg[h * 12 + k - 28]);
                else if (k < 52) val = f2bf(s_kg[h * 12 + k - 40]);
            }
            o[u] = val;
        }
        unsigned short* dst = (side ? khat : qhat) + (((size_t)b * 12 + h) * 512 + i) * 64 + 2 * s2;
        *(ushort2*)dst = make_ushort2(o[0], o[1]);
    }
}

// ---------------- k_qk ----------------
__global__ __launch_bounds__(256) void k_qk(
    const unsigned short* __restrict__ qhat, const unsigned short* __restrict__ khat,
    const float* __restrict__ qn2, const float* __restrict__ kn2,
    const float* __restrict__ hw, float* __restrict__ plog)
{
    int w = threadIdx.x >> 6, lane = threadIdx.x & 63;
    int bh = blockIdx.x;
    int i0 = (blockIdx.y >> 3) * 64;
    int j0 = (blockIdx.y & 7) * 64;
    int r = lane & 15, kq = lane >> 4;
    float sp = log1pf(expf(hw[bh % 12]));
    float m = WPT * sp;
    float coef = -0.5f * m;

    const unsigned short* ap = qhat + ((size_t)bh * 512 + i0 + w * 16 + r) * 64 + kq * 8;
    short8 a0 = *(const short8*)(ap);
    short8 a1 = *(const short8*)(ap + 32);
    const unsigned short* bpb = khat + ((size_t)bh * 512 + j0 + r) * 64 + kq * 8;
    f32x4 acc[4];
    #pragma unroll
    for (int jt = 0; jt < 4; ++jt) {
        short8 b0 = *(const short8*)(bpb + (size_t)jt * 1024);
        short8 b1 = *(const short8*)(bpb + (size_t)jt * 1024 + 32);
        f32x4 a = {0.f, 0.f, 0.f, 0.f};
        a = __builtin_amdgcn_mfma_f32_16x16x32_bf16(a0, b0, a, 0, 0, 0);
        a = __builtin_amdgcn_mfma_f32_16x16x32_bf16(a1, b1, a, 0, 0, 0);
        acc[jt] = a;
    }
    int crow = i0 + w * 16 + kq * 4;
    const float* qn = qn2 + (size_t)bh * 512;
    const float* kn = kn2 + (size_t)bh * 512;
    #pragma unroll
    for (int jt = 0; jt < 4; ++jt) {
        int ccol = j0 + jt * 16 + r;
        float knv = kn[ccol];
        #pragma unroll
        for (int ii = 0; ii < 4; ++ii)
            plog[((size_t)bh * 512 + crow + ii) * 512 + ccol] =
                m * acc[jt][ii] + coef * (qn[crow + ii] + knv);
    }
}

// ---------------- k_av: bias MFMA + plog + softmax -> attnb ; out_pair MFMA (swizzled LDS-T B) ----------------
// grid 1024 (row_i), 512 thr
__global__ __launch_bounds__(512) void k_av(
    const float* __restrict__ pair,
    const unsigned short* __restrict__ wbb, const float* __restrict__ bb,
    const float* __restrict__ plog,
    unsigned short* __restrict__ attnb, unsigned short* __restrict__ featsb)
{
    // union: attn12[12][521] f32 (25008 B) until attnb written; then ldsT[128][264] bf16 (67584 B)
    __shared__ __align__(16) unsigned char smem_raw[67584];
    float (*attn12)[521] = (float(*)[521])smem_raw;
    unsigned short* ldsT = (unsigned short*)smem_raw;

    const int t = threadIdx.x;
    const int row_i = blockIdx.x;
    const int b = row_i >> 9;
    const int i_loc = row_i & 511;
    const int w = t >> 6, lane = t & 63;
    const int r = lane & 15, kq = lane >> 4;

    // ---- Phase 0a: bias via MFMA (8 waves x 4 tiles of 16 j-rows)
    {
        const unsigned short* bp = wbb + r * 128 + kq * 8;
        short8 bfrag[4];
        #pragma unroll
        for (int ks = 0; ks < 4; ++ks) bfrag[ks] = *(const short8*)(bp + ks * 32);
        float bbv = (r < 12) ? bb[r] : 0.f;
        #pragma unroll
        for (int tt = 0; tt < 4; ++tt) {
            int tile = w + tt * 8;
            const float* ap = pair + ((size_t)row_i * NN + tile * 16 + r) * CZD + kq * 8;
            float4 p[8];
            #pragma unroll
            for (int ks = 0; ks < 4; ++ks) {
                p[2 * ks]     = *(const float4*)(ap + ks * 32);
                p[2 * ks + 1] = *(const float4*)(ap + ks * 32 + 4);
            }
            f32x4 acc = {0.f, 0.f, 0.f, 0.f};
            #pragma unroll
            for (int ks = 0; ks < 4; ++ks) {
                short8 av;
                av[0] = (short)f2bf(p[2*ks].x);   av[1] = (short)f2bf(p[2*ks].y);
                av[2] = (short)f2bf(p[2*ks].z);   av[3] = (short)f2bf(p[2*ks].w);
                av[4] = (short)f2bf(p[2*ks+1].x); av[5] = (short)f2bf(p[2*ks+1].y);
                av[6] = (short)f2bf(p[2*ks+1].z); av[7] = (short)f2bf(p[2*ks+1].w);
                acc = __builtin_amdgcn_mfma_f32_16x16x32_bf16(av, bfrag[ks], acc, 0, 0, 0);
            }
            if (r < 12) {
                #pragma unroll
                for (int ii = 0; ii < 4; ++ii)
                    attn12[r][tile * 16 + kq * 4 + ii] = RS3 * (acc[ii] + bbv);
            }
        }
    }
    __syncthreads();

    // ---- Phase 0b: += plog
    #pragma unroll
    for (int it = 0; it < 3; ++it) {
        int idx4 = it * 512 + t;
        int h = idx4 >> 7;
        int j4 = (idx4 & 127) * 4;
        const float* lp = plog + (((size_t)b * 12 + h) * 512 + i_loc) * 512 + j4;
        float4 lv = *(const float4*)lp;
        attn12[h][j4 + 0] += lv.x;
        attn12[h][j4 + 1] += lv.y;
        attn12[h][j4 + 2] += lv.z;
        attn12[h][j4 + 3] += lv.w;
    }
    __syncthreads();

    // ---- softmax
    for (int hh = w; hh < 12; hh += 8) {
        float vreg[8];
        float mx = -1e30f;
        #pragma unroll
        for (int s = 0; s < 8; ++s) { vreg[s] = attn12[hh][lane + 64 * s]; mx = fmaxf(mx, vreg[s]); }
        #pragma unroll
        for (int off = 32; off >= 1; off >>= 1) mx = fmaxf(mx, __shfl_xor(mx, off, 64));
        float ssum = 0.f;
        #pragma unroll
        for (int s = 0; s < 8; ++s) { vreg[s] = __expf(vreg[s] - mx); ssum += vreg[s]; }
        #pragma unroll
        for (int off = 32; off >= 1; off >>= 1) ssum += __shfl_xor(ssum, off, 64);
        float inv = 1.0f / ssum;
        #pragma unroll
        for (int s = 0; s < 8; ++s) attn12[hh][lane + 64 * s] = vreg[s] * inv;
    }
    __syncthreads();

    // ---- attn12 -> attnb (bf16 coalesced)
    for (int idx = t; idx < 768; idx += 512) {
        int h = idx >> 6, jc = idx & 63;
        ushort4 o0, o1;
        o0.x = f2bf(attn12[h][jc * 8 + 0]); o0.y = f2bf(attn12[h][jc * 8 + 1]);
        o0.z = f2bf(attn12[h][jc * 8 + 2]); o0.w = f2bf(attn12[h][jc * 8 + 3]);
        o1.x = f2bf(attn12[h][jc * 8 + 4]); o1.y = f2bf(attn12[h][jc * 8 + 5]);
        o1.z = f2bf(attn12[h][jc * 8 + 6]); o1.w = f2bf(attn12[h][jc * 8 + 7]);
        unsigned short* gp = attnb + (((size_t)(b * 12 + h) * 512 + i_loc)) * 512 + jc * 8;
        *(ushort4*)gp = o0;
        *(ushort4*)(gp + 4) = o1;
    }
    __syncthreads();   // attn12 dead; ldsT may now overwrite smem

    // ---- out_pair via MFMA, B = pair^T staged in LDS (2 stages of 256 j), XOR-swizzled
    {
        const int d0 = w * 16;
        const int hr = (r < 12) ? r : 11;
        const unsigned short* arow = attnb + (((size_t)(b * 12 + hr) * 512 + i_loc)) * 512;
        const int dg = t & 7;        // d-group: 16 d's
        const int jq = t >> 3;       // 0..63 -> j0 = jq*4
        const int j0l = jq * 4;
        f32x4 acc = {0.f, 0.f, 0.f, 0.f};
        for (int stage = 0; stage < 2; ++stage) {
            const float* srcs = pair + (size_t)row_i * NN * CZD
                              + (size_t)(stage * 256 + j0l) * CZD + dg * 16;
            // barrier before overwriting LDS (stage 0: after attnb sync above it's safe,
            // but stage 1 must wait for stage-0 MFMA reads)
            if (stage == 1) __syncthreads();
            #pragma unroll
            for (int u = 0; u < 4; ++u) {
                float4 v0 = *(const float4*)(srcs + 0 * CZD + u * 4);
                float4 v1 = *(const float4*)(srcs + 1 * CZD + u * 4);
                float4 v2 = *(const float4*)(srcs + 2 * CZD + u * 4);
                float4 v3 = *(const float4*)(srcs + 3 * CZD + u * 4);
                const float* f0 = (const float*)&v0;
                const float* f1 = (const float*)&v1;
                const float* f2 = (const float*)&v2;
                const float* f3 = (const float*)&v3;
                #pragma unroll
                for (int e = 0; e < 4; ++e) {
                    int d = dg * 16 + u * 4 + e;
                    ushort4 ov;
                    ov.x = f2bf(f0[e]); ov.y = f2bf(f1[e]);
                    ov.z = f2bf(f2[e]); ov.w = f2bf(f3[e]);
                    int idx = d * 264 + j0l;
                    idx ^= ((d >> 4) & 7) << 4;
                    *(ushort4*)(ldsT + idx) = ov;
                }
            }
            __syncthreads();
            #pragma unroll
            for (int ks = 0; ks < 8; ++ks) {
                short8 av = *(const short8*)(arow + stage * 256 + ks * 32 + kq * 8);
                int idx = (d0 + r) * 264 + ks * 32 + kq * 8;
                idx ^= (((d0 + r) >> 4) & 7) << 4;
                short8 bv = *(const short8*)(ldsT + idx);
                acc = __builtin_amdgcn_mfma_f32_16x16x32_bf16(av, bv, acc, 0, 0, 0);
            }
        }
        unsigned short* frow = featsb + (size_t)row_i * FEATD;
        if (kq < 3) {
            #pragma unroll
            for (int ii = 0; ii < 4; ++ii) {
                int h = kq * 4 + ii;    // 0..11
                frow[576 + h * CZD + d0 + r] = f2bf(acc[ii]);
            }
        }
    }
}

// ---------------- k_avg: AV GEMM + fused rp_l/norms ----------------
__global__ __launch_bounds__(512) void k_avg(
    const unsigned short* __restrict__ attnb, const unsigned short* __restrict__ vallT2,
    const float* __restrict__ rot, const float* __restrict__ trans,
    unsigned short* __restrict__ featsb)
{
    __shared__ float rp_s[32][49];
    int bh = blockIdx.x;
    int itile = blockIdx.y;
    int b = bh / 12, h = bh % 12;
    int t = threadIdx.x;
    int w = t >> 6, lane = t & 63;
    int mt = w >> 2, nt = w & 3;
    int r = lane & 15, kq = lane >> 4;
    int i0 = itile * 32 + mt * 16;
    const unsigned short* ap = attnb + ((size_t)bh * 512 + i0 + r) * 512 + kq * 8;
    const unsigned short* bp = vallT2 + ((size_t)bh * 64 + nt * 16 + r) * 512 + kq * 8;
    f32x4 acc = {0.f, 0.f, 0.f, 0.f};
    #pragma unroll
    for (int ks = 0; ks < 16; ++ks) {
        short8 av = *(const short8*)(ap + ks * 32);
        short8 bv = *(const short8*)(bp + ks * 32);
        acc = __builtin_amdgcn_mfma_f32_16x16x32_bf16(av, bv, acc, 0, 0, 0);
    }
    int cp = nt * 16 + r;
    #pragma unroll
    for (int ii = 0; ii < 4; ++ii) {
        int il = mt * 16 + kq * 4 + ii;
        if (nt == 0) {
            size_t rowg = (size_t)b * 512 + itile * 32 + il;
            featsb[rowg * FEATD + h * 16 + r] = f2bf(acc[ii]);
        } else {
            rp_s[il][cp - 16] = acc[ii];
        }
    }
    __syncthreads();
    if (t < 256) {
        int il = t >> 3, p = t & 7;
        size_t rowg = (size_t)b * 512 + itile * 32 + il;
        const float* R = rot + rowg * 9;
        const float* T = trans + rowg * 3;
        float g0 = rp_s[il][p * 3 + 0] + rp_s[il][24 + p * 3 + 0];
        float g1 = rp_s[il][p * 3 + 1] + rp_s[il][24 + p * 3 + 1];
        float g2 = rp_s[il][p * 3 + 2] + rp_s[il][24 + p * 3 + 2];
        float d0 = g0 - T[0], d1 = g1 - T[1], d2v = g2 - T[2];
        float l0 = R[0] * d0 + R[3] * d1 + R[6] * d2v;
        float l1 = R[1] * d0 + R[4] * d1 + R[7] * d2v;
        float l2 = R[2] * d0 + R[5] * d1 + R[8] * d2v;
        float nrm = sqrtf(l0 * l0 + l1 * l1 + l2 * l2 + 1e-8f);
        unsigned short* frow = featsb + rowg * FEATD;
        int hp = h * 8 + p;
        frow[192 + hp] = f2bf(l0);
        frow[288 + hp] = f2bf(l1);
        frow[384 + hp] = f2bf(l2);
        frow[480 + hp] = f2bf(nrm);
    }
}

// ---------------- k_gemm2 ----------------
__global__ __launch_bounds__(256) void k_gemm2(
    const unsigned short* __restrict__ A, const unsigned short* __restrict__ Bm,
    const float* __restrict__ bo, float* __restrict__ out)
{
    int w = threadIdx.x >> 6, lane = threadIdx.x & 63;
    int rt = blockIdx.x;
    int ct = blockIdx.y * 4 + w;
    int r = lane & 15, kq = lane >> 4;
    const unsigned short* ap = A  + (size_t)(rt * 16 + r) * FEATD + kq * 8;
    const unsigned short* bp = Bm + (size_t)(ct * 16 + r) * FEATD + kq * 8;
    f32x4 acc = {0.f, 0.f, 0.f, 0.f};
    #pragma unroll 2
    for (int ks = 0; ks < 66; ++ks) {
        short8 av = *(const short8*)(ap + ks * 32);
        short8 bv = *(const short8*)(bp + ks * 32);
        acc = __builtin_amdgcn_mfma_f32_16x16x32_bf16(av, bv, acc, 0, 0, 0);
    }
    int crow = rt * 16 + kq * 4;
    int ccol = ct * 16 + r;
    float bv = bo[ccol];
    #pragma unroll
    for (int i = 0; i < 4; ++i)
        out[(size_t)(crow + i) * CSD + ccol] = acc[i] + bv;
}

extern "C" void kernel_launch(void* const* d_in, const int* in_sizes, int n_in,
                              void* d_out, int out_size, void* d_ws, size_t ws_size,
                              hipStream_t stream) {
    const float* single = (const float*)d_in[0];
    const float* pair   = (const float*)d_in[1];
    const float* rot    = (const float*)d_in[2];
    const float* trans  = (const float*)d_in[3];
    const float* wq     = (const float*)d_in[4];
    const float* bq     = (const float*)d_in[5];
    const float* wkv    = (const float*)d_in[6];
    const float* bkv    = (const float*)d_in[7];
    const float* wqp    = (const float*)d_in[8];
    const float* bqp    = (const float*)d_in[9];
    const float* wkvp   = (const float*)d_in[10];
    const float* bkvp   = (const float*)d_in[11];
    const float* wb     = (const float*)d_in[12];
    const float* bb     = (const float*)d_in[13];
    const float* wo     = (const float*)d_in[14];
    const float* bo     = (const float*)d_in[15];
    const float* hw     = (const float*)d_in[16];
    float* out = (float*)d_out;

    float* ws = (float*)d_ws;
    float* plog    = ws;                          // 6,291,456
    float* projraw = ws;                          // (alias, disjoint lifetime)
    unsigned short* qhat = (unsigned short*)(ws + 6291456);
    unsigned short* khat = (unsigned short*)(ws + 6684672);
    float* qn2     = ws + 7077888;
    float* kn2     = ws + 7090176;
    unsigned short* featsb  = (unsigned short*)(ws + 7102464);
    unsigned short* singleb = (unsigned short*)(ws + 8183808);
    unsigned short* wallb   = (unsigned short*)(ws + 8380416);
    unsigned short* wob     = (unsigned short*)(ws + 8601600);
    unsigned short* wbb     = (unsigned short*)(ws + 9007104);
    unsigned short* vallT2  = (unsigned short*)(ws + 9008128);
    unsigned short* attnb   = (unsigned short*)(ws + 9401344);   // 6,291,456 bf16
    // total ~12.5M f32 slots = 50.2 MB

    hipLaunchKernelGGL(k_cvt, dim3(1610), dim3(256), 0, stream,
                       single, wq, wkv, wqp, wkvp, wo, wb, singleb, wallb, wob, wbb);
    hipLaunchKernelGGL(k_gemm1, dim3(64, 18), dim3(256), 0, stream, singleb, wallb, projraw);
    hipLaunchKernelGGL(k_post, dim3(1024), dim3(256), 0, stream,
                       projraw, rot, trans, hw, bq, bkv, bqp, bkvp,
                       vallT2, qhat, khat, qn2, kn2);
    hipLaunchKernelGGL(k_qk, dim3(24, 64), dim3(256), 0, stream,
                       qhat, khat, qn2, kn2, hw, plog);
    hipLaunchKernelGGL(k_av, dim3(1024), dim3(512), 0, stream,
                       pair, wbb, bb, plog, attnb, featsb);
    hipLaunchKernelGGL(k_avg, dim3(24, 16), dim3(512), 0, stream,
                       attnb, vallT2, rot, trans, featsb);
    hipLaunchKernelGGL(k_gemm2, dim3(64, 6), dim3(256), 0, stream, featsb, wob, bo, out);
}

// Round 12
// 199.026 us; speedup vs baseline: 1.0246x; 1.0246x over previous
//
#include <hip/hip_runtime.h>
#include <hip/hip_bf16.h>
#include <math.h>

#define NB 2
#define NN 512
#define CSD 384
#define CZD 128
#define NH 12
#define NC 16
#define NPQ 4
#define NPV 8
#define HC 192
#define QPDIM 144
#define FEATD 2112
#define WPT 0.13608276348795434f   // sqrt(1/(3*PQ*4.5))
#define RS3C 0.14433756729740643f  // sqrt(1/(3*C))
#define RS3 0.5773502691896258f    // sqrt(1/3)

typedef __attribute__((ext_vector_type(8))) short short8;
typedef __attribute__((ext_vector_type(4))) float f32x4;

static __device__ inline unsigned short f2bf(float x) {
    __hip_bfloat16 h = __float2bfloat16(x);
    return *reinterpret_cast<unsigned short*>(&h);
}
static __device__ inline unsigned short bflo(float x) {
    __hip_bfloat16 h = __float2bfloat16(x);
    return f2bf(x - __bfloat162float(h));
}

// ---------------- k_cvt ----------------
#define R_S0 393216
#define R_S1 (R_S0 + 73728)
#define R_S2 (R_S1 + 147456)
#define R_S3 (R_S2 + 55296)
#define R_S4 (R_S3 + 165888)
#define R_S5 (R_S4 + 811008)
#define R_S6 (R_S5 + 2048)
__global__ __launch_bounds__(256) void k_cvt(
    const float* __restrict__ single, const float* __restrict__ wq,
    const float* __restrict__ wkv, const float* __restrict__ wqp,
    const float* __restrict__ wkvp, const float* __restrict__ wo,
    const float* __restrict__ wb,
    unsigned short* __restrict__ singleb, unsigned short* __restrict__ wallb,
    unsigned short* __restrict__ wob, unsigned short* __restrict__ wbb)
{
    int gid = blockIdx.x * 256 + threadIdx.x;
    int e = gid * 4;
    if (e >= R_S6) return;
    if (e >= R_S5) {
        int c = e - R_S5;
        int hh = c >> 7;
        ushort4 o;
        if (hh < 12) {
            float4 v = *(const float4*)(wb + hh * 128 + (c & 127));
            o.x = f2bf(v.x); o.y = f2bf(v.y); o.z = f2bf(v.z); o.w = f2bf(v.w);
        } else { o.x = 0; o.y = 0; o.z = 0; o.w = 0; }
        *(ushort4*)(wbb + c) = o;
        return;
    }
    const float* src; unsigned short* dst;
    if (e < R_S0)      { src = single + e;          dst = singleb + e; }
    else if (e < R_S1) { src = wq + (e - R_S0);     dst = wallb + (e - R_S0); }
    else if (e < R_S2) { src = wkv + (e - R_S1);    dst = wallb + 73728 + (e - R_S1); }
    else if (e < R_S3) { src = wqp + (e - R_S2);    dst = wallb + 221184 + (e - R_S2); }
    else if (e < R_S4) { src = wkvp + (e - R_S3);   dst = wallb + 276480 + (e - R_S3); }
    else               { src = wo + (e - R_S4);     dst = wob + (e - R_S4); }
    float4 v = *(const float4*)src;
    ushort4 o;
    o.x = f2bf(v.x); o.y = f2bf(v.y); o.z = f2bf(v.z); o.w = f2bf(v.w);
    *(ushort4*)dst = o;
}

// ---------------- k_gemm1 ----------------
__global__ __launch_bounds__(256) void k_gemm1(
    const unsigned short* __restrict__ A, const unsigned short* __restrict__ Bm,
    float* __restrict__ Cr)
{
    int w = threadIdx.x >> 6, lane = threadIdx.x & 63;
    int rt = blockIdx.x;
    int ct = blockIdx.y * 4 + w;
    int r = lane & 15, kq = lane >> 4;
    const unsigned short* ap = A  + (size_t)(rt * 16 + r) * 384 + kq * 8;
    const unsigned short* bp = Bm + (size_t)(ct * 16 + r) * 384 + kq * 8;
    f32x4 acc = {0.f, 0.f, 0.f, 0.f};
    #pragma unroll 4
    for (int ks = 0; ks < 12; ++ks) {
        short8 av = *(const short8*)(ap + ks * 32);
        short8 bv = *(const short8*)(bp + ks * 32);
        acc = __builtin_amdgcn_mfma_f32_16x16x32_bf16(av, bv, acc, 0, 0, 0);
    }
    int crow = rt * 16 + kq * 4;
    int ccol = ct * 16 + r;
    #pragma unroll
    for (int i = 0; i < 4; ++i)
        Cr[(size_t)(crow + i) * 1152 + ccol] = acc[i];
}

// ---------------- k_post ----------------
__global__ __launch_bounds__(256) void k_post(
    const float* __restrict__ praw, const float* __restrict__ rot, const float* __restrict__ trans,
    const float* __restrict__ hw,
    const float* __restrict__ bq, const float* __restrict__ bkv,
    const float* __restrict__ bqp, const float* __restrict__ bkvp,
    unsigned short* __restrict__ vallT2,
    unsigned short* __restrict__ qhat, unsigned short* __restrict__ khat,
    float* __restrict__ qn2, float* __restrict__ kn2)
{
    __shared__ float s_q[192], s_k[192], s_v[192], s_qp[QPDIM], s_kvp[432];
    __shared__ float s_qg[144], s_kg[144], s_vg[288];
    __shared__ float s_sh[12];
    const int t = threadIdx.x;
    const int row = blockIdx.x;
    const int b = row >> 9;
    const int i = row & 511;

    if (t < 12) {
        float sp = log1pf(expf(hw[t]));
        s_sh[t] = RS3C / (WPT * sp);
    }
    const float* pr = praw + (size_t)row * 1152;
    for (int idx = t; idx < 1152; idx += 256) {
        float v = pr[idx];
        if (idx < 192) {
            s_q[idx] = v + bq[idx];
        } else if (idx < 576) {
            int f = idx - 192; float x = v + bkv[f];
            int h = f >> 5, cc = f & 31;
            if (cc < 16) s_k[h * 16 + cc] = x;
            else         s_v[h * 16 + cc - 16] = x;
        } else if (idx < 720) {
            int f = idx - 576; s_qp[f] = v + bqp[f];
        } else {
            int f = idx - 720; s_kvp[f] = v + bkvp[f];
        }
    }
    __syncthreads();

    if (t < 192) {
        const float* R = rot + (size_t)row * 9;
        const float* T = trans + (size_t)row * 3;
        float lx, ly, lz; float* dst;
        if (t < 48) {
            lx = s_qp[t]; ly = s_qp[48 + t]; lz = s_qp[96 + t];
            dst = s_qg + t * 3;
        } else if (t < 96) {
            int idx = t - 48; int fb = (idx >> 2) * 12 + (idx & 3);
            lx = s_kvp[fb]; ly = s_kvp[144 + fb]; lz = s_kvp[288 + fb];
            dst = s_kg + idx * 3;
        } else {
            int idx = t - 96; int fb = (idx >> 3) * 12 + 4 + (idx & 7);
            lx = s_kvp[fb]; ly = s_kvp[144 + fb]; lz = s_kvp[288 + fb];
            dst = s_vg + idx * 3;
        }
        dst[0] = R[0] * lx + R[1] * ly + R[2] * lz + T[0];
        dst[1] = R[3] * lx + R[4] * ly + R[5] * lz + T[1];
        dst[2] = R[6] * lx + R[7] * ly + R[8] * lz + T[2];
    }
    __syncthreads();

    if (t < 24) {
        int h = t % 12;
        const float* g = (t < 12) ? (s_qg + h * 12) : (s_kg + h * 12);
        float s = 0.f;
        #pragma unroll
        for (int e = 0; e < 12; ++e) s += g[e] * g[e];
        float* dst = (t < 12) ? qn2 : kn2;
        dst[((size_t)b * 12 + h) * 512 + i] = s;
    }

    for (int c = t; c < 768; c += 256) {
        int h = c >> 6, cp = c & 63;
        unsigned short v;
        if (cp < 16)      v = f2bf(s_v[h * 16 + cp]);
        else if (cp < 40) v = f2bf(s_vg[h * 24 + cp - 16]);
        else              v = bflo(s_vg[h * 24 + cp - 40]);
        vallT2[((size_t)(b * 12 + h) * 64 + cp) * 512 + i] = v;
    }

    for (int idx = t; idx < 768; idx += 256) {
        int side = idx >= 384;
        int li = side ? (idx - 384) : idx;
        int h = li >> 5, s2 = li & 31;
        unsigned short o[2];
        #pragma unroll
        for (int u = 0; u < 2; ++u) {
            int k = 2 * s2 + u;
            unsigned short val = 0;
            if (!side) {
                if (k < 16)      val = f2bf(s_sh[h] * s_q[h * 16 + k]);
                else if (k < 28) val = f2bf(s_qg[h * 12 + k - 16]);
                else if (k < 40) val = f2bf(s_qg[h * 12 + k - 28]);
                else if (k < 52) val = bflo(s_qg[h * 12 + k - 40]);
            } else {
                if (k < 16)      val = f2bf(s_k[h * 16 + k]);
                else if (k < 28) val = f2bf(s_kg[h * 12 + k - 16]);
                else if (k < 40) val = bflo(s_kg[h * 12 + k - 28]);
                else if (k < 52) val = f2bf(s_kg[h * 12 + k - 40]);
            }
            o[u] = val;
        }
        unsigned short* dst = (side ? khat : qhat) + (((size_t)b * 12 + h) * 512 + i) * 64 + 2 * s2;
        *(ushort2*)dst = make_ushort2(o[0], o[1]);
    }
}

// ---------------- k_qk ----------------
__global__ __launch_bounds__(256) void k_qk(
    const unsigned short* __restrict__ qhat, const unsigned short* __restrict__ khat,
    const float* __restrict__ qn2, const float* __restrict__ kn2,
    const float* __restrict__ hw, float* __restrict__ plog)
{
    int w = threadIdx.x >> 6, lane = threadIdx.x & 63;
    int bh = blockIdx.x;
    int i0 = (blockIdx.y >> 3) * 64;
    int j0 = (blockIdx.y & 7) * 64;
    int r = lane & 15, kq = lane >> 4;
    float sp = log1pf(expf(hw[bh % 12]));
    float m = WPT * sp;
    float coef = -0.5f * m;

    const unsigned short* ap = qhat + ((size_t)bh * 512 + i0 + w * 16 + r) * 64 + kq * 8;
    short8 a0 = *(const short8*)(ap);
    short8 a1 = *(const short8*)(ap + 32);
    const unsigned short* bpb = khat + ((size_t)bh * 512 + j0 + r) * 64 + kq * 8;
    f32x4 acc[4];
    #pragma unroll
    for (int jt = 0; jt < 4; ++jt) {
        short8 b0 = *(const short8*)(bpb + (size_t)jt * 1024);
        short8 b1 = *(const short8*)(bpb + (size_t)jt * 1024 + 32);
        f32x4 a = {0.f, 0.f, 0.f, 0.f};
        a = __builtin_amdgcn_mfma_f32_16x16x32_bf16(a0, b0, a, 0, 0, 0);
        a = __builtin_amdgcn_mfma_f32_16x16x32_bf16(a1, b1, a, 0, 0, 0);
        acc[jt] = a;
    }
    int crow = i0 + w * 16 + kq * 4;
    const float* qn = qn2 + (size_t)bh * 512;
    const float* kn = kn2 + (size_t)bh * 512;
    #pragma unroll
    for (int jt = 0; jt < 4; ++jt) {
        int ccol = j0 + jt * 16 + r;
        float knv = kn[ccol];
        #pragma unroll
        for (int ii = 0; ii < 4; ++ii)
            plog[((size_t)bh * 512 + crow + ii) * 512 + ccol] =
                m * acc[jt][ii] + coef * (qn[crow + ii] + knv);
    }
}

// ---------------- k_av2: bias MFMA + plog + softmax -> attnb ----------------
// grid 1024 (row_i), 512 thr; 25 KB LDS -> 4 blocks/CU
__global__ __launch_bounds__(512) void k_av2(
    const float* __restrict__ pair,
    const unsigned short* __restrict__ wbb, const float* __restrict__ bb,
    const float* __restrict__ plog,
    unsigned short* __restrict__ attnb)
{
    __shared__ float attn12[12][521];

    const int t = threadIdx.x;
    const int row_i = blockIdx.x;
    const int b = row_i >> 9;
    const int i_loc = row_i & 511;
    const int w = t >> 6, lane = t & 63;
    const int r = lane & 15, kq = lane >> 4;

    // ---- Phase 0a: bias via MFMA (8 waves x 4 tiles of 16 j-rows)
    {
        const unsigned short* bp = wbb + r * 128 + kq * 8;
        short8 bfrag[4];
        #pragma unroll
        for (int ks = 0; ks < 4; ++ks) bfrag[ks] = *(const short8*)(bp + ks * 32);
        float bbv = (r < 12) ? bb[r] : 0.f;
        #pragma unroll
        for (int tt = 0; tt < 4; ++tt) {
            int tile = w + tt * 8;
            const float* ap = pair + ((size_t)row_i * NN + tile * 16 + r) * CZD + kq * 8;
            float4 p[8];
            #pragma unroll
            for (int ks = 0; ks < 4; ++ks) {
                p[2 * ks]     = *(const float4*)(ap + ks * 32);
                p[2 * ks + 1] = *(const float4*)(ap + ks * 32 + 4);
            }
            f32x4 acc = {0.f, 0.f, 0.f, 0.f};
            #pragma unroll
            for (int ks = 0; ks < 4; ++ks) {
                short8 av;
                av[0] = (short)f2bf(p[2*ks].x);   av[1] = (short)f2bf(p[2*ks].y);
                av[2] = (short)f2bf(p[2*ks].z);   av[3] = (short)f2bf(p[2*ks].w);
                av[4] = (short)f2bf(p[2*ks+1].x); av[5] = (short)f2bf(p[2*ks+1].y);
                av[6] = (short)f2bf(p[2*ks+1].z); av[7] = (short)f2bf(p[2*ks+1].w);
                acc = __builtin_amdgcn_mfma_f32_16x16x32_bf16(av, bfrag[ks], acc, 0, 0, 0);
            }
            if (r < 12) {
                #pragma unroll
                for (int ii = 0; ii < 4; ++ii)
                    attn12[r][tile * 16 + kq * 4 + ii] = RS3 * (acc[ii] + bbv);
            }
        }
    }
    __syncthreads();

    // ---- Phase 0b: += plog
    #pragma unroll
    for (int it = 0; it < 3; ++it) {
        int idx4 = it * 512 + t;
        int h = idx4 >> 7;
        int j4 = (idx4 & 127) * 4;
        const float* lp = plog + (((size_t)b * 12 + h) * 512 + i_loc) * 512 + j4;
        float4 lv = *(const float4*)lp;
        attn12[h][j4 + 0] += lv.x;
        attn12[h][j4 + 1] += lv.y;
        attn12[h][j4 + 2] += lv.z;
        attn12[h][j4 + 3] += lv.w;
    }
    __syncthreads();

    // ---- softmax
    for (int hh = w; hh < 12; hh += 8) {
        float vreg[8];
        float mx = -1e30f;
        #pragma unroll
        for (int s = 0; s < 8; ++s) { vreg[s] = attn12[hh][lane + 64 * s]; mx = fmaxf(mx, vreg[s]); }
        #pragma unroll
        for (int off = 32; off >= 1; off >>= 1) mx = fmaxf(mx, __shfl_xor(mx, off, 64));
        float ssum = 0.f;
        #pragma unroll
        for (int s = 0; s < 8; ++s) { vreg[s] = __expf(vreg[s] - mx); ssum += vreg[s]; }
        #pragma unroll
        for (int off = 32; off >= 1; off >>= 1) ssum += __shfl_xor(ssum, off, 64);
        float inv = 1.0f / ssum;
        #pragma unroll
        for (int s = 0; s < 8; ++s) attn12[hh][lane + 64 * s] = vreg[s] * inv;
    }
    __syncthreads();

    // ---- attn12 -> attnb (bf16 coalesced)
    for (int idx = t; idx < 768; idx += 512) {
        int h = idx >> 6, jc = idx & 63;
        ushort4 o0, o1;
        o0.x = f2bf(attn12[h][jc * 8 + 0]); o0.y = f2bf(attn12[h][jc * 8 + 1]);
        o0.z = f2bf(attn12[h][jc * 8 + 2]); o0.w = f2bf(attn12[h][jc * 8 + 3]);
        o1.x = f2bf(attn12[h][jc * 8 + 4]); o1.y = f2bf(attn12[h][jc * 8 + 5]);
        o1.z = f2bf(attn12[h][jc * 8 + 6]); o1.w = f2bf(attn12[h][jc * 8 + 7]);
        unsigned short* gp = attnb + (((size_t)(b * 12 + h) * 512 + i_loc)) * 512 + jc * 8;
        *(ushort4*)gp = o0;
        *(ushort4*)(gp + 4) = o1;
    }
}

// ---------------- k_op: out_pair via MFMA, direct L2/L3 gather (no LDS, no barriers) ----------------
// grid (1024, 2), 256 thr (4 waves); wave w -> d0 = (dh*4 + w)*16
__global__ __launch_bounds__(256) void k_op(
    const float* __restrict__ pair, const unsigned short* __restrict__ attnb,
    unsigned short* __restrict__ featsb)
{
    const int t = threadIdx.x;
    const int row_i = blockIdx.x;
    const int dh = blockIdx.y;
    const int b = row_i >> 9;
    const int i_loc = row_i & 511;
    const int w = t >> 6, lane = t & 63;
    const int r = lane & 15, kq = lane >> 4;
    const int d0 = (dh * 4 + w) * 16;
    const int hr = (r < 12) ? r : 11;   // A rows 12..15 feed discarded C rows only
    const unsigned short* arow = attnb + ((size_t)(b * 12 + hr) * 512 + i_loc) * 512 + kq * 8;
    const float* pbase = pair + (size_t)row_i * NN * CZD + d0 + r;
    f32x4 acc = {0.f, 0.f, 0.f, 0.f};
    for (int ks = 0; ks < 16; ++ks) {
        int jb = ks * 32 + kq * 8;
        float x0 = pbase[(size_t)(jb + 0) * CZD];
        float x1 = pbase[(size_t)(jb + 1) * CZD];
        float x2 = pbase[(size_t)(jb + 2) * CZD];
        float x3 = pbase[(size_t)(jb + 3) * CZD];
        float x4 = pbase[(size_t)(jb + 4) * CZD];
        float x5 = pbase[(size_t)(jb + 5) * CZD];
        float x6 = pbase[(size_t)(jb + 6) * CZD];
        float x7 = pbase[(size_t)(jb + 7) * CZD];
        short8 av = *(const short8*)(arow + ks * 32);
        short8 bv;
        bv[0] = (short)f2bf(x0); bv[1] = (short)f2bf(x1);
        bv[2] = (short)f2bf(x2); bv[3] = (short)f2bf(x3);
        bv[4] = (short)f2bf(x4); bv[5] = (short)f2bf(x5);
        bv[6] = (short)f2bf(x6); bv[7] = (short)f2bf(x7);
        acc = __builtin_amdgcn_mfma_f32_16x16x32_bf16(av, bv, acc, 0, 0, 0);
    }
    unsigned short* frow = featsb + (size_t)row_i * FEATD;
    if (kq < 3) {
        #pragma unroll
        for (int ii = 0; ii < 4; ++ii) {
            int h = kq * 4 + ii;    // 0..11
            frow[576 + h * CZD + d0 + r] = f2bf(acc[ii]);
        }
    }
}

// ---------------- k_avg: AV GEMM + fused rp_l/norms ----------------
__global__ __launch_bounds__(512) void k_avg(
    const unsigned short* __restrict__ attnb, const unsigned short* __restrict__ vallT2,
    const float* __restrict__ rot, const float* __restrict__ trans,
    unsigned short* __restrict__ featsb)
{
    __shared__ float rp_s[32][49];
    int bh = blockIdx.x;
    int itile = blockIdx.y;
    int b = bh / 12, h = bh % 12;
    int t = threadIdx.x;
    int w = t >> 6, lane = t & 63;
    int mt = w >> 2, nt = w & 3;
    int r = lane & 15, kq = lane >> 4;
    int i0 = itile * 32 + mt * 16;
    const unsigned short* ap = attnb + ((size_t)bh * 512 + i0 + r) * 512 + kq * 8;
    const unsigned short* bp = vallT2 + ((size_t)bh * 64 + nt * 16 + r) * 512 + kq * 8;
    f32x4 acc = {0.f, 0.f, 0.f, 0.f};
    #pragma unroll
    for (int ks = 0; ks < 16; ++ks) {
        short8 av = *(const short8*)(ap + ks * 32);
        short8 bv = *(const short8*)(bp + ks * 32);
        acc = __builtin_amdgcn_mfma_f32_16x16x32_bf16(av, bv, acc, 0, 0, 0);
    }
    int cp = nt * 16 + r;
    #pragma unroll
    for (int ii = 0; ii < 4; ++ii) {
        int il = mt * 16 + kq * 4 + ii;
        if (nt == 0) {
            size_t rowg = (size_t)b * 512 + itile * 32 + il;
            featsb[rowg * FEATD + h * 16 + r] = f2bf(acc[ii]);
        } else {
            rp_s[il][cp - 16] = acc[ii];
        }
    }
    __syncthreads();
    if (t < 256) {
        int il = t >> 3, p = t & 7;
        size_t rowg = (size_t)b * 512 + itile * 32 + il;
        const float* R = rot + rowg * 9;
        const float* T = trans + rowg * 3;
        float g0 = rp_s[il][p * 3 + 0] + rp_s[il][24 + p * 3 + 0];
        float g1 = rp_s[il][p * 3 + 1] + rp_s[il][24 + p * 3 + 1];
        float g2 = rp_s[il][p * 3 + 2] + rp_s[il][24 + p * 3 + 2];
        float d0 = g0 - T[0], d1 = g1 - T[1], d2v = g2 - T[2];
        float l0 = R[0] * d0 + R[3] * d1 + R[6] * d2v;
        float l1 = R[1] * d0 + R[4] * d1 + R[7] * d2v;
        float l2 = R[2] * d0 + R[5] * d1 + R[8] * d2v;
        float nrm = sqrtf(l0 * l0 + l1 * l1 + l2 * l2 + 1e-8f);
        unsigned short* frow = featsb + rowg * FEATD;
        int hp = h * 8 + p;
        frow[192 + hp] = f2bf(l0);
        frow[288 + hp] = f2bf(l1);
        frow[384 + hp] = f2bf(l2);
        frow[480 + hp] = f2bf(nrm);
    }
}

// ---------------- k_gemm2 ----------------
__global__ __launch_bounds__(256) void k_gemm2(
    const unsigned short* __restrict__ A, const unsigned short* __restrict__ Bm,
    const float* __restrict__ bo, float* __restrict__ out)
{
    int w = threadIdx.x >> 6, lane = threadIdx.x & 63;
    int rt = blockIdx.x;
    int ct = blockIdx.y * 4 + w;
    int r = lane & 15, kq = lane >> 4;
    const unsigned short* ap = A  + (size_t)(rt * 16 + r) * FEATD + kq * 8;
    const unsigned short* bp = Bm + (size_t)(ct * 16 + r) * FEATD + kq * 8;
    f32x4 acc = {0.f, 0.f, 0.f, 0.f};
    #pragma unroll 2
    for (int ks = 0; ks < 66; ++ks) {
        short8 av = *(const short8*)(ap + ks * 32);
        short8 bv = *(const short8*)(bp + ks * 32);
        acc = __builtin_amdgcn_mfma_f32_16x16x32_bf16(av, bv, acc, 0, 0, 0);
    }
    int crow = rt * 16 + kq * 4;
    int ccol = ct * 16 + r;
    float bv = bo[ccol];
    #pragma unroll
    for (int i = 0; i < 4; ++i)
        out[(size_t)(crow + i) * CSD + ccol] = acc[i] + bv;
}

extern "C" void kernel_launch(void* const* d_in, const int* in_sizes, int n_in,
                              void* d_out, int out_size, void* d_ws, size_t ws_size,
                              hipStream_t stream) {
    const float* single = (const float*)d_in[0];
    const float* pair   = (const float*)d_in[1];
    const float* rot    = (const float*)d_in[2];
    const float* trans  = (const float*)d_in[3];
    const float* wq     = (const float*)d_in[4];
    const float* bq     = (const float*)d_in[5];
    const float* wkv    = (const float*)d_in[6];
    const float* bkv    = (const float*)d_in[7];
    const float* wqp    = (const float*)d_in[8];
    const float* bqp    = (const float*)d_in[9];
    const float* wkvp   = (const float*)d_in[10];
    const float* bkvp   = (const float*)d_in[11];
    const float* wb     = (const float*)d_in[12];
    const float* bb     = (const float*)d_in[13];
    const float* wo     = (const float*)d_in[14];
    const float* bo     = (const float*)d_in[15];
    const float* hw     = (const float*)d_in[16];
    float* out = (float*)d_out;

    float* ws = (float*)d_ws;
    float* plog    = ws;                          // 6,291,456
    float* projraw = ws;                          // (alias, disjoint lifetime)
    unsigned short* qhat = (unsigned short*)(ws + 6291456);
    unsigned short* khat = (unsigned short*)(ws + 6684672);
    float* qn2     = ws + 7077888;
    float* kn2     = ws + 7090176;
    unsigned short* featsb  = (unsigned short*)(ws + 7102464);
    unsigned short* singleb = (unsigned short*)(ws + 8183808);
    unsigned short* wallb   = (unsigned short*)(ws + 8380416);
    unsigned short* wob     = (unsigned short*)(ws + 8601600);
    unsigned short* wbb     = (unsigned short*)(ws + 9007104);
    unsigned short* vallT2  = (unsigned short*)(ws + 9008128);
    unsigned short* attnb   = (unsigned short*)(ws + 9401344);   // 6,291,456 bf16
    // total ~12.5M f32 slots = 50.2 MB

    hipLaunchKernelGGL(k_cvt, dim3(1610), dim3(256), 0, stream,
                       single, wq, wkv, wqp, wkvp, wo, wb, singleb, wallb, wob, wbb);
    hipLaunchKernelGGL(k_gemm1, dim3(64, 18), dim3(256), 0, stream, singleb, wallb, projraw);
    hipLaunchKernelGGL(k_post, dim3(1024), dim3(256), 0, stream,
                       projraw, rot, trans, hw, bq, bkv, bqp, bkvp,
                       vallT2, qhat, khat, qn2, kn2);
    hipLaunchKernelGGL(k_qk, dim3(24, 64), dim3(256), 0, stream,
                       qhat, khat, qn2, kn2, hw, plog);
    hipLaunchKernelGGL(k_av2, dim3(1024), dim3(512), 0, stream,
                       pair, wbb, bb, plog, attnb);
    hipLaunchKernelGGL(k_op, dim3(1024, 2), dim3(256), 0, stream, pair, attnb, featsb);
    hipLaunchKernelGGL(k_avg, dim3(24, 16), dim3(512), 0, stream,
                       attnb, vallT2, rot, trans, featsb);
    hipLaunchKernelGGL(k_gemm2, dim3(64, 6), dim3(256), 0, stream, featsb, wob, bo, out);
}

// Round 13
// 185.512 us; speedup vs baseline: 1.0992x; 1.0728x over previous
//
#include <hip/hip_runtime.h>
#include <hip/hip_bf16.h>
#include <math.h>

#define NB 2
#define NN 512
#define CSD 384
#define CZD 128
#define NH 12
#define NC 16
#define NPQ 4
#define NPV 8
#define HC 192
#define QPDIM 144
#define FEATD 2112
#define WPT 0.13608276348795434f   // sqrt(1/(3*PQ*4.5))
#define RS3C 0.14433756729740643f  // sqrt(1/(3*C))
#define RS3 0.5773502691896258f    // sqrt(1/3)

typedef __attribute__((ext_vector_type(8))) short short8;
typedef __attribute__((ext_vector_type(4))) float f32x4;

static __device__ inline unsigned short f2bf(float x) {
    __hip_bfloat16 h = __float2bfloat16(x);
    return *reinterpret_cast<unsigned short*>(&h);
}
static __device__ inline unsigned short bflo(float x) {
    __hip_bfloat16 h = __float2bfloat16(x);
    return f2bf(x - __bfloat162float(h));
}

// ---------------- k_cvt ----------------
#define R_S0 393216
#define R_S1 (R_S0 + 73728)
#define R_S2 (R_S1 + 147456)
#define R_S3 (R_S2 + 55296)
#define R_S4 (R_S3 + 165888)
#define R_S5 (R_S4 + 811008)
#define R_S6 (R_S5 + 2048)
__global__ __launch_bounds__(256) void k_cvt(
    const float* __restrict__ single, const float* __restrict__ wq,
    const float* __restrict__ wkv, const float* __restrict__ wqp,
    const float* __restrict__ wkvp, const float* __restrict__ wo,
    const float* __restrict__ wb,
    unsigned short* __restrict__ singleb, unsigned short* __restrict__ wallb,
    unsigned short* __restrict__ wob, unsigned short* __restrict__ wbb)
{
    int gid = blockIdx.x * 256 + threadIdx.x;
    int e = gid * 4;
    if (e >= R_S6) return;
    if (e >= R_S5) {
        int c = e - R_S5;
        int hh = c >> 7;
        ushort4 o;
        if (hh < 12) {
            float4 v = *(const float4*)(wb + hh * 128 + (c & 127));
            o.x = f2bf(v.x); o.y = f2bf(v.y); o.z = f2bf(v.z); o.w = f2bf(v.w);
        } else { o.x = 0; o.y = 0; o.z = 0; o.w = 0; }
        *(ushort4*)(wbb + c) = o;
        return;
    }
    const float* src; unsigned short* dst;
    if (e < R_S0)      { src = single + e;          dst = singleb + e; }
    else if (e < R_S1) { src = wq + (e - R_S0);     dst = wallb + (e - R_S0); }
    else if (e < R_S2) { src = wkv + (e - R_S1);    dst = wallb + 73728 + (e - R_S1); }
    else if (e < R_S3) { src = wqp + (e - R_S2);    dst = wallb + 221184 + (e - R_S2); }
    else if (e < R_S4) { src = wkvp + (e - R_S3);   dst = wallb + 276480 + (e - R_S3); }
    else               { src = wo + (e - R_S4);     dst = wob + (e - R_S4); }
    float4 v = *(const float4*)src;
    ushort4 o;
    o.x = f2bf(v.x); o.y = f2bf(v.y); o.z = f2bf(v.z); o.w = f2bf(v.w);
    *(ushort4*)dst = o;
}

// ---------------- k_gemm1 ----------------
__global__ __launch_bounds__(256) void k_gemm1(
    const unsigned short* __restrict__ A, const unsigned short* __restrict__ Bm,
    float* __restrict__ Cr)
{
    int w = threadIdx.x >> 6, lane = threadIdx.x & 63;
    int rt = blockIdx.x;
    int ct = blockIdx.y * 4 + w;
    int r = lane & 15, kq = lane >> 4;
    const unsigned short* ap = A  + (size_t)(rt * 16 + r) * 384 + kq * 8;
    const unsigned short* bp = Bm + (size_t)(ct * 16 + r) * 384 + kq * 8;
    f32x4 acc = {0.f, 0.f, 0.f, 0.f};
    #pragma unroll 4
    for (int ks = 0; ks < 12; ++ks) {
        short8 av = *(const short8*)(ap + ks * 32);
        short8 bv = *(const short8*)(bp + ks * 32);
        acc = __builtin_amdgcn_mfma_f32_16x16x32_bf16(av, bv, acc, 0, 0, 0);
    }
    int crow = rt * 16 + kq * 4;
    int ccol = ct * 16 + r;
    #pragma unroll
    for (int i = 0; i < 4; ++i)
        Cr[(size_t)(crow + i) * 1152 + ccol] = acc[i];
}

// ---------------- k_post ----------------
__global__ __launch_bounds__(256) void k_post(
    const float* __restrict__ praw, const float* __restrict__ rot, const float* __restrict__ trans,
    const float* __restrict__ hw,
    const float* __restrict__ bq, const float* __restrict__ bkv,
    const float* __restrict__ bqp, const float* __restrict__ bkvp,
    unsigned short* __restrict__ vallT2,
    unsigned short* __restrict__ qhat, unsigned short* __restrict__ khat,
    float* __restrict__ qn2, float* __restrict__ kn2)
{
    __shared__ float s_q[192], s_k[192], s_v[192], s_qp[QPDIM], s_kvp[432];
    __shared__ float s_qg[144], s_kg[144], s_vg[288];
    __shared__ float s_sh[12];
    const int t = threadIdx.x;
    const int row = blockIdx.x;
    const int b = row >> 9;
    const int i = row & 511;

    if (t < 12) {
        float sp = log1pf(expf(hw[t]));
        s_sh[t] = RS3C / (WPT * sp);
    }
    const float* pr = praw + (size_t)row * 1152;
    for (int idx = t; idx < 1152; idx += 256) {
        float v = pr[idx];
        if (idx < 192) {
            s_q[idx] = v + bq[idx];
        } else if (idx < 576) {
            int f = idx - 192; float x = v + bkv[f];
            int h = f >> 5, cc = f & 31;
            if (cc < 16) s_k[h * 16 + cc] = x;
            else         s_v[h * 16 + cc - 16] = x;
        } else if (idx < 720) {
            int f = idx - 576; s_qp[f] = v + bqp[f];
        } else {
            int f = idx - 720; s_kvp[f] = v + bkvp[f];
        }
    }
    __syncthreads();

    if (t < 192) {
        const float* R = rot + (size_t)row * 9;
        const float* T = trans + (size_t)row * 3;
        float lx, ly, lz; float* dst;
        if (t < 48) {
            lx = s_qp[t]; ly = s_qp[48 + t]; lz = s_qp[96 + t];
            dst = s_qg + t * 3;
        } else if (t < 96) {
            int idx = t - 48; int fb = (idx >> 2) * 12 + (idx & 3);
            lx = s_kvp[fb]; ly = s_kvp[144 + fb]; lz = s_kvp[288 + fb];
            dst = s_kg + idx * 3;
        } else {
            int idx = t - 96; int fb = (idx >> 3) * 12 + 4 + (idx & 7);
            lx = s_kvp[fb]; ly = s_kvp[144 + fb]; lz = s_kvp[288 + fb];
            dst = s_vg + idx * 3;
        }
        dst[0] = R[0] * lx + R[1] * ly + R[2] * lz + T[0];
        dst[1] = R[3] * lx + R[4] * ly + R[5] * lz + T[1];
        dst[2] = R[6] * lx + R[7] * ly + R[8] * lz + T[2];
    }
    __syncthreads();

    if (t < 24) {
        int h = t % 12;
        const float* g = (t < 12) ? (s_qg + h * 12) : (s_kg + h * 12);
        float s = 0.f;
        #pragma unroll
        for (int e = 0; e < 12; ++e) s += g[e] * g[e];
        float* dst = (t < 12) ? qn2 : kn2;
        dst[((size_t)b * 12 + h) * 512 + i] = s;
    }

    for (int c = t; c < 768; c += 256) {
        int h = c >> 6, cp = c & 63;
        unsigned short v;
        if (cp < 16)      v = f2bf(s_v[h * 16 + cp]);
        else if (cp < 40) v = f2bf(s_vg[h * 24 + cp - 16]);
        else              v = bflo(s_vg[h * 24 + cp - 40]);
        vallT2[((size_t)(b * 12 + h) * 64 + cp) * 512 + i] = v;
    }

    for (int idx = t; idx < 768; idx += 256) {
        int side = idx >= 384;
        int li = side ? (idx - 384) : idx;
        int h = li >> 5, s2 = li & 31;
        unsigned short o[2];
        #pragma unroll
        for (int u = 0; u < 2; ++u) {
            int k = 2 * s2 + u;
            unsigned short val = 0;
            if (!side) {
                if (k < 16)      val = f2bf(s_sh[h] * s_q[h * 16 + k]);
                else if (k < 28) val = f2bf(s_qg[h * 12 + k - 16]);
                else if (k < 40) val = f2bf(s_qg[h * 12 + k - 28]);
                else if (k < 52) val = bflo(s_qg[h * 12 + k - 40]);
            } else {
                if (k < 16)      val = f2bf(s_k[h * 16 + k]);
                else if (k < 28) val = f2bf(s_kg[h * 12 + k - 16]);
                else if (k < 40) val = bflo(s_kg[h * 12 + k - 28]);
                else if (k < 52) val = f2bf(s_kg[h * 12 + k - 40]);
            }
            o[u] = val;
        }
        unsigned short* dst = (side ? khat : qhat) + (((size_t)b * 12 + h) * 512 + i) * 64 + 2 * s2;
        *(ushort2*)dst = make_ushort2(o[0], o[1]);
    }
}

// ---------------- k_qk ----------------
__global__ __launch_bounds__(256) void k_qk(
    const unsigned short* __restrict__ qhat, const unsigned short* __restrict__ khat,
    const float* __restrict__ qn2, const float* __restrict__ kn2,
    const float* __restrict__ hw, float* __restrict__ plog)
{
    int w = threadIdx.x >> 6, lane = threadIdx.x & 63;
    int bh = blockIdx.x;
    int i0 = (blockIdx.y >> 3) * 64;
    int j0 = (blockIdx.y & 7) * 64;
    int r = lane & 15, kq = lane >> 4;
    float sp = log1pf(expf(hw[bh % 12]));
    float m = WPT * sp;
    float coef = -0.5f * m;

    const unsigned short* ap = qhat + ((size_t)bh * 512 + i0 + w * 16 + r) * 64 + kq * 8;
    short8 a0 = *(const short8*)(ap);
    short8 a1 = *(const short8*)(ap + 32);
    const unsigned short* bpb = khat + ((size_t)bh * 512 + j0 + r) * 64 + kq * 8;
    f32x4 acc[4];
    #pragma unroll
    for (int jt = 0; jt < 4; ++jt) {
        short8 b0 = *(const short8*)(bpb + (size_t)jt * 1024);
        short8 b1 = *(const short8*)(bpb + (size_t)jt * 1024 + 32);
        f32x4 a = {0.f, 0.f, 0.f, 0.f};
        a = __builtin_amdgcn_mfma_f32_16x16x32_bf16(a0, b0, a, 0, 0, 0);
        a = __builtin_amdgcn_mfma_f32_16x16x32_bf16(a1, b1, a, 0, 0, 0);
        acc[jt] = a;
    }
    int crow = i0 + w * 16 + kq * 4;
    const float* qn = qn2 + (size_t)bh * 512;
    const float* kn = kn2 + (size_t)bh * 512;
    #pragma unroll
    for (int jt = 0; jt < 4; ++jt) {
        int ccol = j0 + jt * 16 + r;
        float knv = kn[ccol];
        #pragma unroll
        for (int ii = 0; ii < 4; ++ii)
            plog[((size_t)bh * 512 + crow + ii) * 512 + ccol] =
                m * acc[jt][ii] + coef * (qn[crow + ii] + knv);
    }
}

// ---------------- k_av: bias MFMA + plog + softmax -> attnb ; out_pair MFMA (direct gather, fused) ----------------
// grid 1024 (row_i), 512 thr  -- the R9-validated 187.6us structure
__global__ __launch_bounds__(512) void k_av(
    const float* __restrict__ pair,
    const unsigned short* __restrict__ wbb, const float* __restrict__ bb,
    const float* __restrict__ plog,
    unsigned short* __restrict__ attnb, unsigned short* __restrict__ featsb)
{
    __shared__ float attn12[12][521];

    const int t = threadIdx.x;
    const int row_i = blockIdx.x;
    const int b = row_i >> 9;
    const int i_loc = row_i & 511;
    const int w = t >> 6, lane = t & 63;
    const int r = lane & 15, kq = lane >> 4;

    // ---- Phase 0a: bias via MFMA (8 waves x 4 tiles of 16 j-rows)
    {
        const unsigned short* bp = wbb + r * 128 + kq * 8;
        short8 bfrag[4];
        #pragma unroll
        for (int ks = 0; ks < 4; ++ks) bfrag[ks] = *(const short8*)(bp + ks * 32);
        float bbv = (r < 12) ? bb[r] : 0.f;
        #pragma unroll
        for (int tt = 0; tt < 4; ++tt) {
            int tile = w + tt * 8;
            const float* ap = pair + ((size_t)row_i * NN + tile * 16 + r) * CZD + kq * 8;
            float4 p[8];
            #pragma unroll
            for (int ks = 0; ks < 4; ++ks) {
                p[2 * ks]     = *(const float4*)(ap + ks * 32);
                p[2 * ks + 1] = *(const float4*)(ap + ks * 32 + 4);
            }
            f32x4 acc = {0.f, 0.f, 0.f, 0.f};
            #pragma unroll
            for (int ks = 0; ks < 4; ++ks) {
                short8 av;
                av[0] = (short)f2bf(p[2*ks].x);   av[1] = (short)f2bf(p[2*ks].y);
                av[2] = (short)f2bf(p[2*ks].z);   av[3] = (short)f2bf(p[2*ks].w);
                av[4] = (short)f2bf(p[2*ks+1].x); av[5] = (short)f2bf(p[2*ks+1].y);
                av[6] = (short)f2bf(p[2*ks+1].z); av[7] = (short)f2bf(p[2*ks+1].w);
                acc = __builtin_amdgcn_mfma_f32_16x16x32_bf16(av, bfrag[ks], acc, 0, 0, 0);
            }
            if (r < 12) {
                #pragma unroll
                for (int ii = 0; ii < 4; ++ii)
                    attn12[r][tile * 16 + kq * 4 + ii] = RS3 * (acc[ii] + bbv);
            }
        }
    }
    __syncthreads();

    // ---- Phase 0b: += plog
    #pragma unroll
    for (int it = 0; it < 3; ++it) {
        int idx4 = it * 512 + t;
        int h = idx4 >> 7;
        int j4 = (idx4 & 127) * 4;
        const float* lp = plog + (((size_t)b * 12 + h) * 512 + i_loc) * 512 + j4;
        float4 lv = *(const float4*)lp;
        attn12[h][j4 + 0] += lv.x;
        attn12[h][j4 + 1] += lv.y;
        attn12[h][j4 + 2] += lv.z;
        attn12[h][j4 + 3] += lv.w;
    }
    __syncthreads();

    // ---- softmax
    for (int hh = w; hh < 12; hh += 8) {
        float vreg[8];
        float mx = -1e30f;
        #pragma unroll
        for (int s = 0; s < 8; ++s) { vreg[s] = attn12[hh][lane + 64 * s]; mx = fmaxf(mx, vreg[s]); }
        #pragma unroll
        for (int off = 32; off >= 1; off >>= 1) mx = fmaxf(mx, __shfl_xor(mx, off, 64));
        float ssum = 0.f;
        #pragma unroll
        for (int s = 0; s < 8; ++s) { vreg[s] = __expf(vreg[s] - mx); ssum += vreg[s]; }
        #pragma unroll
        for (int off = 32; off >= 1; off >>= 1) ssum += __shfl_xor(ssum, off, 64);
        float inv = 1.0f / ssum;
        #pragma unroll
        for (int s = 0; s < 8; ++s) attn12[hh][lane + 64 * s] = vreg[s] * inv;
    }
    __syncthreads();

    // ---- attn12 -> attnb (bf16 coalesced)
    for (int idx = t; idx < 768; idx += 512) {
        int h = idx >> 6, jc = idx & 63;
        ushort4 o0, o1;
        o0.x = f2bf(attn12[h][jc * 8 + 0]); o0.y = f2bf(attn12[h][jc * 8 + 1]);
        o0.z = f2bf(attn12[h][jc * 8 + 2]); o0.w = f2bf(attn12[h][jc * 8 + 3]);
        o1.x = f2bf(attn12[h][jc * 8 + 4]); o1.y = f2bf(attn12[h][jc * 8 + 5]);
        o1.z = f2bf(attn12[h][jc * 8 + 6]); o1.w = f2bf(attn12[h][jc * 8 + 7]);
        unsigned short* gp = attnb + (((size_t)(b * 12 + h) * 512 + i_loc)) * 512 + jc * 8;
        *(ushort4*)gp = o0;
        *(ushort4*)(gp + 4) = o1;
    }
    __syncthreads();

    // ---- out_pair via MFMA: wave w -> d-tile d0 = w*16; A = attnb (L1-hot), B gathered from L2-hot pair slab
    {
        const int d0 = w * 16;
        const int hr = (r < 12) ? r : 11;
        const unsigned short* arow = attnb + (((size_t)(b * 12 + hr) * 512 + i_loc)) * 512 + kq * 8;
        const float* pbase = pair + (size_t)row_i * NN * CZD + d0 + r;
        f32x4 acc = {0.f, 0.f, 0.f, 0.f};
        for (int ks = 0; ks < 16; ++ks) {
            int jb = ks * 32 + kq * 8;
            float x0 = pbase[(size_t)(jb + 0) * CZD];
            float x1 = pbase[(size_t)(jb + 1) * CZD];
            float x2 = pbase[(size_t)(jb + 2) * CZD];
            float x3 = pbase[(size_t)(jb + 3) * CZD];
            float x4 = pbase[(size_t)(jb + 4) * CZD];
            float x5 = pbase[(size_t)(jb + 5) * CZD];
            float x6 = pbase[(size_t)(jb + 6) * CZD];
            float x7 = pbase[(size_t)(jb + 7) * CZD];
            short8 av = *(const short8*)(arow + ks * 32);
            short8 bv;
            bv[0] = (short)f2bf(x0); bv[1] = (short)f2bf(x1);
            bv[2] = (short)f2bf(x2); bv[3] = (short)f2bf(x3);
            bv[4] = (short)f2bf(x4); bv[5] = (short)f2bf(x5);
            bv[6] = (short)f2bf(x6); bv[7] = (short)f2bf(x7);
            acc = __builtin_amdgcn_mfma_f32_16x16x32_bf16(av, bv, acc, 0, 0, 0);
        }
        unsigned short* frow = featsb + (size_t)row_i * FEATD;
        if (kq < 3) {
            #pragma unroll
            for (int ii = 0; ii < 4; ++ii) {
                int h = kq * 4 + ii;    // 0..11
                frow[576 + h * CZD + d0 + r] = f2bf(acc[ii]);
            }
        }
    }
}

// ---------------- k_avg: AV GEMM + fused rp_l/norms ----------------
__global__ __launch_bounds__(512) void k_avg(
    const unsigned short* __restrict__ attnb, const unsigned short* __restrict__ vallT2,
    const float* __restrict__ rot, const float* __restrict__ trans,
    unsigned short* __restrict__ featsb)
{
    __shared__ float rp_s[32][49];
    int bh = blockIdx.x;
    int itile = blockIdx.y;
    int b = bh / 12, h = bh % 12;
    int t = threadIdx.x;
    int w = t >> 6, lane = t & 63;
    int mt = w >> 2, nt = w & 3;
    int r = lane & 15, kq = lane >> 4;
    int i0 = itile * 32 + mt * 16;
    const unsigned short* ap = attnb + ((size_t)bh * 512 + i0 + r) * 512 + kq * 8;
    const unsigned short* bp = vallT2 + ((size_t)bh * 64 + nt * 16 + r) * 512 + kq * 8;
    f32x4 acc = {0.f, 0.f, 0.f, 0.f};
    #pragma unroll
    for (int ks = 0; ks < 16; ++ks) {
        short8 av = *(const short8*)(ap + ks * 32);
        short8 bv = *(const short8*)(bp + ks * 32);
        acc = __builtin_amdgcn_mfma_f32_16x16x32_bf16(av, bv, acc, 0, 0, 0);
    }
    int cp = nt * 16 + r;
    #pragma unroll
    for (int ii = 0; ii < 4; ++ii) {
        int il = mt * 16 + kq * 4 + ii;
        if (nt == 0) {
            size_t rowg = (size_t)b * 512 + itile * 32 + il;
            featsb[rowg * FEATD + h * 16 + r] = f2bf(acc[ii]);
        } else {
            rp_s[il][cp - 16] = acc[ii];
        }
    }
    __syncthreads();
    if (t < 256) {
        int il = t >> 3, p = t & 7;
        size_t rowg = (size_t)b * 512 + itile * 32 + il;
        const float* R = rot + rowg * 9;
        const float* T = trans + rowg * 3;
        float g0 = rp_s[il][p * 3 + 0] + rp_s[il][24 + p * 3 + 0];
        float g1 = rp_s[il][p * 3 + 1] + rp_s[il][24 + p * 3 + 1];
        float g2 = rp_s[il][p * 3 + 2] + rp_s[il][24 + p * 3 + 2];
        float d0 = g0 - T[0], d1 = g1 - T[1], d2v = g2 - T[2];
        float l0 = R[0] * d0 + R[3] * d1 + R[6] * d2v;
        float l1 = R[1] * d0 + R[4] * d1 + R[7] * d2v;
        float l2 = R[2] * d0 + R[5] * d1 + R[8] * d2v;
        float nrm = sqrtf(l0 * l0 + l1 * l1 + l2 * l2 + 1e-8f);
        unsigned short* frow = featsb + rowg * FEATD;
        int hp = h * 8 + p;
        frow[192 + hp] = f2bf(l0);
        frow[288 + hp] = f2bf(l1);
        frow[384 + hp] = f2bf(l2);
        frow[480 + hp] = f2bf(nrm);
    }
}

// ---------------- k_gemm2 ----------------
__global__ __launch_bounds__(256) void k_gemm2(
    const unsigned short* __restrict__ A, const unsigned short* __restrict__ Bm,
    const float* __restrict__ bo, float* __restrict__ out)
{
    int w = threadIdx.x >> 6, lane = threadIdx.x & 63;
    int rt = blockIdx.x;
    int ct = blockIdx.y * 4 + w;
    int r = lane & 15, kq = lane >> 4;
    const unsigned short* ap = A  + (size_t)(rt * 16 + r) * FEATD + kq * 8;
    const unsigned short* bp = Bm + (size_t)(ct * 16 + r) * FEATD + kq * 8;
    f32x4 acc = {0.f, 0.f, 0.f, 0.f};
    #pragma unroll 2
    for (int ks = 0; ks < 66; ++ks) {
        short8 av = *(const short8*)(ap + ks * 32);
        short8 bv = *(const short8*)(bp + ks * 32);
        acc = __builtin_amdgcn_mfma_f32_16x16x32_bf16(av, bv, acc, 0, 0, 0);
    }
    int crow = rt * 16 + kq * 4;
    int ccol = ct * 16 + r;
    float bv = bo[ccol];
    #pragma unroll
    for (int i = 0; i < 4; ++i)
        out[(size_t)(crow + i) * CSD + ccol] = acc[i] + bv;
}

extern "C" void kernel_launch(void* const* d_in, const int* in_sizes, int n_in,
                              void* d_out, int out_size, void* d_ws, size_t ws_size,
                              hipStream_t stream) {
    const float* single = (const float*)d_in[0];
    const float* pair   = (const float*)d_in[1];
    const float* rot    = (const float*)d_in[2];
    const float* trans  = (const float*)d_in[3];
    const float* wq     = (const float*)d_in[4];
    const float* bq     = (const float*)d_in[5];
    const float* wkv    = (const float*)d_in[6];
    const float* bkv    = (const float*)d_in[7];
    const float* wqp    = (const float*)d_in[8];
    const float* bqp    = (const float*)d_in[9];
    const float* wkvp   = (const float*)d_in[10];
    const float* bkvp   = (const float*)d_in[11];
    const float* wb     = (const float*)d_in[12];
    const float* bb     = (const float*)d_in[13];
    const float* wo     = (const float*)d_in[14];
    const float* bo     = (const float*)d_in[15];
    const float* hw     = (const float*)d_in[16];
    float* out = (float*)d_out;

    float* ws = (float*)d_ws;
    float* plog    = ws;                          // 6,291,456
    float* projraw = ws;                          // (alias, disjoint lifetime)
    unsigned short* qhat = (unsigned short*)(ws + 6291456);
    unsigned short* khat = (unsigned short*)(ws + 6684672);
    float* qn2     = ws + 7077888;
    float* kn2     = ws + 7090176;
    unsigned short* featsb  = (unsigned short*)(ws + 7102464);
    unsigned short* singleb = (unsigned short*)(ws + 8183808);
    unsigned short* wallb   = (unsigned short*)(ws + 8380416);
    unsigned short* wob     = (unsigned short*)(ws + 8601600);
    unsigned short* wbb     = (unsigned short*)(ws + 9007104);
    unsigned short* vallT2  = (unsigned short*)(ws + 9008128);
    unsigned short* attnb   = (unsigned short*)(ws + 9401344);   // 6,291,456 bf16
    // total ~12.5M f32 slots = 50.2 MB

    hipLaunchKernelGGL(k_cvt, dim3(1610), dim3(256), 0, stream,
                       single, wq, wkv, wqp, wkvp, wo, wb, singleb, wallb, wob, wbb);
    hipLaunchKernelGGL(k_gemm1, dim3(64, 18), dim3(256), 0, stream, singleb, wallb, projraw);
    hipLaunchKernelGGL(k_post, dim3(1024), dim3(256), 0, stream,
                       projraw, rot, trans, hw, bq, bkv, bqp, bkvp,
                       vallT2, qhat, khat, qn2, kn2);
    hipLaunchKernelGGL(k_qk, dim3(24, 64), dim3(256), 0, stream,
                       qhat, khat, qn2, kn2, hw, plog);
    hipLaunchKernelGGL(k_av, dim3(1024), dim3(512), 0, stream,
                       pair, wbb, bb, plog, attnb, featsb);
    hipLaunchKernelGGL(k_avg, dim3(24, 16), dim3(512), 0, stream,
                       attnb, vallT2, rot, trans, featsb);
    hipLaunchKernelGGL(k_gemm2, dim3(64, 6), dim3(256), 0, stream, featsb, wob, bo, out);
}